// Round 1
// baseline (652.083 us; speedup 1.0000x reference)
//
#include <hip/hip_runtime.h>
#include <math.h>

#define NN 256
#define DD 128
#define HH 512

// ---------------- workspace layout (float offsets) ----------------
#define WS_H1    0         // [2][256][512]
#define WS_EMB   262144    // [2][256][128]
#define WS_AE    327680    // [2][256][512]
#define WS_CE    589824    // [2][256][512]
#define WS_PP    851968    // [2][256][512]
#define WS_QM    1114112   // [2][256][512]
#define WS_S     1376256   // [2][256][512]
#define WS_INTRA 1638400   // [2][256][128]
#define WS_CROSS 1703936   // [2][256][128]
#define WS_UPD   1769472   // [2][256][128]
#define WS_R     1835008   // [2][128]
#define WS_PB    1835264   // [512]
#define WS_SB    1835776   // [2][128]
// total 1836032 floats = ~7.0 MB

__device__ __forceinline__ float f4c(const float4& v, int q) {
  return q == 0 ? v.x : q == 1 ? v.y : q == 2 ? v.z : v.w;
}

// C[g][row][c] = act( ascale*A_g[row,:] @ B + cb[c] + rowm[row,c] )
__global__ void rowgemm(const float* __restrict__ A0, const float* __restrict__ A1, int lda,
                        const float* __restrict__ B, int ldb,
                        const float* __restrict__ cb,
                        const float* __restrict__ rowm, int ldr,
                        float* __restrict__ C, int cstride, int ldc,
                        int Nc, int K, int relu, float ascale)
{
  __shared__ float Ar[HH];
  const int row = blockIdx.x;
  const int g = blockIdx.z;
  const float* A = g ? A1 : A0;
  for (int k = threadIdx.x; k < K; k += 256) Ar[k] = A[row * lda + k] * ascale;
  __syncthreads();
  for (int c = threadIdx.x; c < Nc; c += 256) {
    float acc = cb ? cb[c] : 0.f;
    if (rowm) acc += rowm[row * ldr + c];
    #pragma unroll 8
    for (int k = 0; k < K; ++k) acc = fmaf(Ar[k], B[k * ldb + c], acc);
    if (relu) acc = fmaxf(acc, 0.f);
    C[g * cstride + row * ldc + c] = acc;
  }
}

// pb[h] = pr_b1[h] + sum_d ee_b2[d] * WE[d][h]   (WE = pr_w1 rows 256..383)
__global__ void prep_pbk(const float* __restrict__ eeb2, const float* __restrict__ prw1,
                         const float* __restrict__ prb1, float* __restrict__ pb)
{
  const int h = blockIdx.x * 256 + threadIdx.x;
  float s = prb1[h];
  for (int d = 0; d < DD; ++d) s += eeb2[d] * prw1[(2 * DD + d) * HH + h];
  pb[h] = s;
}

// ---------------- fused heavy edge kernel ----------------
// block: 2 i's x all 256 j's (4 tiles of 64 j).  grid (128,1,2).
// S[i][h] = sum_j relu( Pp[i][h] + Qm[j][h] + (relu(Ae[i]+Ce[j]) @ ee_w2) @ WE [h] )
#define S1_TT 5184          // TtT [32][132]  (T^T: [kk][e])
#define S1_WT 9408          // Wt  [32][128]
#define S2_WE 5184          // WEc [64][128]  (aliases TtT/Wt)
#define SM_UT 13504         // UT  [128][132] (U^T: [ucol][e])
#define SM_RED 3072         // Red [16][132]
#define SM_TOT 30400        // floats = 121.6 KB

__global__ __launch_bounds__(256, 1)
void heavyk(const float* __restrict__ AeG, const float* __restrict__ CeG,
            const float* __restrict__ PpG, const float* __restrict__ QmG,
            const float* __restrict__ W2,   // ee_w2 [512][128]
            const float* __restrict__ PR1,  // pr_w1 [384][512], WE = rows 256..383
            float* __restrict__ SG)
{
  __shared__ float sm[SM_TOT];
  const int g = blockIdx.z;
  const int ib = blockIdx.x * 2;
  const int tid = threadIdx.x;
  const float* Ae = AeG + g * (NN * HH);
  const float* Ce = CeG + g * (NN * HH);
  const float* Pp = PpG + g * (NN * HH);
  const float* Qm = QmG + g * (NN * HH);
  float* S = SG + g * (NN * HH);

  for (int idx = tid; idx < 2 * HH; idx += 256) {
    int ii = idx >> 9, h = idx & (HH - 1);
    sm[idx]        = Ae[(ib + ii) * HH + h];   // AES @0
    sm[1024 + idx] = Pp[(ib + ii) * HH + h];   // PPS @1024
    sm[2048 + idx] = 0.f;                      // SAC @2048
  }
  __syncthreads();

  const int ty = tid >> 4, tx = tid & 15;
  const int e0 = ty * 8;       // 8 edges per thread
  const int c0 = tx * 8;       // 8 cols per thread
  const int ii0 = e0 >> 6;     // which of the 2 i's
  const int kkb = (tid & 7) * 4;        // generation: 4 kk
  const int eg0 = (tid >> 3) * 4;       // generation: 4 e
  const int gii = eg0 >> 6;

  for (int jt = 0; jt < 4; ++jt) {
    const int jb = jt * 64;

    // ---------- stage 1: U[e][c] = sum_k relu(Ae[i]+Ce[j])[k] * ee_w2[k][c] ----------
    float acc[8][8];
    #pragma unroll
    for (int r = 0; r < 8; ++r)
      #pragma unroll
      for (int c = 0; c < 8; ++c) acc[r][c] = 0.f;

    for (int kc = 0; kc < 16; ++kc) {
      const int k0 = kc * 32;
      __syncthreads();
      { // generate T^T chunk
        float4 aef = *(const float4*)&sm[gii * HH + k0 + kkb];
        const float* cbase = Ce + (jb + (eg0 & 63)) * HH + k0 + kkb;
        float4 cef0 = *(const float4*)(cbase);
        float4 cef1 = *(const float4*)(cbase + HH);
        float4 cef2 = *(const float4*)(cbase + 2 * HH);
        float4 cef3 = *(const float4*)(cbase + 3 * HH);
        #pragma unroll
        for (int q = 0; q < 4; ++q) {
          float a = f4c(aef, q);
          float4 v;
          v.x = fmaxf(a + f4c(cef0, q), 0.f);
          v.y = fmaxf(a + f4c(cef1, q), 0.f);
          v.z = fmaxf(a + f4c(cef2, q), 0.f);
          v.w = fmaxf(a + f4c(cef3, q), 0.f);
          *(float4*)&sm[S1_TT + (kkb + q) * 132 + eg0] = v;
        }
      }
      { // load ee_w2 chunk (contiguous)
        const float4* src = (const float4*)(W2 + k0 * DD);
        float4* dst = (float4*)&sm[S1_WT];
        #pragma unroll
        for (int i = 0; i < 4; ++i) dst[tid + i * 256] = src[tid + i * 256];
      }
      __syncthreads();
      #pragma unroll 4
      for (int kk = 0; kk < 32; ++kk) {
        const float* ab = &sm[S1_TT + kk * 132 + e0];
        float4 a0 = *(const float4*)ab;
        float4 a1 = *(const float4*)(ab + 4);
        const float* wb = &sm[S1_WT + kk * DD + c0];
        float4 w0 = *(const float4*)wb;
        float4 w1 = *(const float4*)(wb + 4);
        float av[8] = {a0.x, a0.y, a0.z, a0.w, a1.x, a1.y, a1.z, a1.w};
        float wv[8] = {w0.x, w0.y, w0.z, w0.w, w1.x, w1.y, w1.z, w1.w};
        #pragma unroll
        for (int r = 0; r < 8; ++r)
          #pragma unroll
          for (int c = 0; c < 8; ++c)
            acc[r][c] = fmaf(av[r], wv[c], acc[r][c]);
      }
    }

    // ---------- write U^T to LDS ----------
    __syncthreads();
    #pragma unroll
    for (int c = 0; c < 8; ++c) {
      float4 u0 = make_float4(acc[0][c], acc[1][c], acc[2][c], acc[3][c]);
      float4 u1 = make_float4(acc[4][c], acc[5][c], acc[6][c], acc[7][c]);
      float* dst = &sm[SM_UT + (c0 + c) * 132 + e0];
      *(float4*)dst = u0;
      *(float4*)(dst + 4) = u1;
    }

    // ---------- stage 2: G = U @ WE, h = relu(Pp+Qm+G), reduce over j ----------
    for (int nc = 0; nc < 4; ++nc) {
      const int nb = nc * 128;
      float acc2[8][8];
      {
        float4 p0 = *(const float4*)&sm[1024 + ii0 * HH + nb + c0];
        float4 p1 = *(const float4*)&sm[1024 + ii0 * HH + nb + c0 + 4];
        #pragma unroll
        for (int r = 0; r < 8; ++r) {
          const float* qb = Qm + (jb + ((e0 + r) & 63)) * HH + nb + c0;
          float4 q0 = *(const float4*)qb;
          float4 q1 = *(const float4*)(qb + 4);
          acc2[r][0] = p0.x + q0.x; acc2[r][1] = p0.y + q0.y;
          acc2[r][2] = p0.z + q0.z; acc2[r][3] = p0.w + q0.w;
          acc2[r][4] = p1.x + q1.x; acc2[r][5] = p1.y + q1.y;
          acc2[r][6] = p1.z + q1.z; acc2[r][7] = p1.w + q1.w;
        }
      }
      #pragma unroll
      for (int kc2 = 0; kc2 < 2; ++kc2) {
        __syncthreads();
        #pragma unroll
        for (int i = 0; i < 8; ++i) { // load WE chunk [64][128]
          int f = tid + i * 256;
          int dl = f >> 5, cf = f & 31;
          ((float4*)&sm[S2_WE])[dl * 32 + cf] =
              *(const float4*)&PR1[(2 * DD + kc2 * 64 + dl) * HH + nb + cf * 4];
        }
        __syncthreads();
        #pragma unroll 4
        for (int kk = 0; kk < 64; ++kk) {
          const float* ab = &sm[SM_UT + (kc2 * 64 + kk) * 132 + e0];
          float4 a0 = *(const float4*)ab;
          float4 a1 = *(const float4*)(ab + 4);
          const float* wb = &sm[S2_WE + kk * DD + c0];
          float4 w0 = *(const float4*)wb;
          float4 w1 = *(const float4*)(wb + 4);
          float av[8] = {a0.x, a0.y, a0.z, a0.w, a1.x, a1.y, a1.z, a1.w};
          float wv[8] = {w0.x, w0.y, w0.z, w0.w, w1.x, w1.y, w1.z, w1.w};
          #pragma unroll
          for (int r = 0; r < 8; ++r)
            #pragma unroll
            for (int c = 0; c < 8; ++c)
              acc2[r][c] = fmaf(av[r], wv[c], acc2[r][c]);
        }
      }
      // epilogue: relu + per-thread j-partial, then cross-thread reduce
      float part[8];
      #pragma unroll
      for (int c = 0; c < 8; ++c) {
        float s = 0.f;
        #pragma unroll
        for (int r = 0; r < 8; ++r) s += fmaxf(acc2[r][c], 0.f);
        part[c] = s;
      }
      *(float4*)&sm[SM_RED + ty * 132 + c0]     = make_float4(part[0], part[1], part[2], part[3]);
      *(float4*)&sm[SM_RED + ty * 132 + c0 + 4] = make_float4(part[4], part[5], part[6], part[7]);
      __syncthreads();
      {
        const int iiR = tid >> 7, cR = tid & 127;
        float s = 0.f;
        #pragma unroll
        for (int t2 = 0; t2 < 8; ++t2) s += sm[SM_RED + (iiR * 8 + t2) * 132 + cR];
        sm[2048 + iiR * HH + nb + cR] += s;
      }
      __syncthreads();
    }
  }

  __syncthreads();
  for (int idx = tid; idx < 2 * HH; idx += 256) {
    int ii = idx >> 9, h = idx & (HH - 1);
    S[(ib + ii) * HH + h] = sm[2048 + idx];
  }
}

// Sb[g][d] = sum_j emb[g][j][d]
__global__ void colsumk(const float* __restrict__ embG, float* __restrict__ Sb)
{
  const int g = blockIdx.x, d = threadIdx.x;
  const float* E = embG + g * NN * DD;
  float s = 0.f;
  for (int j = 0; j < NN; ++j) s += E[j * DD + d];
  Sb[g * DD + d] = s;
}

// cross[dir][i][d] = (sum_j b[j,d]*exp(a[i,d]*b[j,d])) / (N * a[i,d] * Sb_b[d])
__global__ void interactk(const float* __restrict__ embG, const float* __restrict__ Sb,
                          float* __restrict__ cross)
{
  const int i = blockIdx.x, dir = blockIdx.y, d = threadIdx.x;
  const float* A = embG + dir * NN * DD;
  const float* B = embG + (1 - dir) * NN * DD;
  float av = A[i * DD + d];
  float acc = 0.f;
  for (int j = 0; j < NN; ++j) {
    float bv = B[j * DD + d];
    acc += bv * expf(av * bv);
  }
  float den = (float)NN * av * Sb[(1 - dir) * DD + d];
  cross[dir * NN * DD + i * DD + d] = acc / den;
}

// upd[g][i][:] = [l2n(emb), l2n(intra), l2n(cross)] @ up_w + up_b
__global__ void updk(const float* __restrict__ emb, const float* __restrict__ intra,
                     const float* __restrict__ cross, const float* __restrict__ upw,
                     const float* __restrict__ upb, float* __restrict__ upd)
{
  const int i = blockIdx.x, g = blockIdx.z, d = threadIdx.x; // 128 threads
  __shared__ float v[3 * DD];
  __shared__ float red[DD];
  const int base = g * NN * DD + i * DD;
  {
    float x = emb[base + d];
    red[d] = x * x; __syncthreads();
    for (int s = 64; s > 0; s >>= 1) { if (d < s) red[d] += red[d + s]; __syncthreads(); }
    v[d] = x / fmaxf(sqrtf(red[0]), 1e-12f);
    __syncthreads();
  }
  {
    float x = intra[base + d];
    red[d] = x * x; __syncthreads();
    for (int s = 64; s > 0; s >>= 1) { if (d < s) red[d] += red[d + s]; __syncthreads(); }
    v[DD + d] = x / fmaxf(sqrtf(red[0]), 1e-12f);
    __syncthreads();
  }
  {
    float x = cross[base + d];
    red[d] = x * x; __syncthreads();
    for (int s = 64; s > 0; s >>= 1) { if (d < s) red[d] += red[d + s]; __syncthreads(); }
    v[2 * DD + d] = x / fmaxf(sqrtf(red[0]), 1e-12f);
    __syncthreads();
  }
  float acc = upb[d];
  #pragma unroll 8
  for (int k = 0; k < 3 * DD; ++k) acc = fmaf(v[k], upw[k * DD + d], acc);
  upd[base + d] = acc;
}

// r[g][:] = sum_i softmax_i(feats@ag_w+ag_b) * upd[g][i][:]
__global__ void aggregatek(const float* __restrict__ updG, const float* __restrict__ agw,
                           const float* __restrict__ agb, float* __restrict__ r)
{
  const int g = blockIdx.x;
  const int t = threadIdx.x; // 256
  const float* U = updG + g * NN * DD;
  __shared__ float mu[DD], lg[NN], red[NN], bcst[1];
  if (t < DD) {
    float s = 0.f;
    for (int j = 0; j < NN; ++j) s += U[j * DD + t];
    mu[t] = s * (1.f / NN);
  }
  __syncthreads();
  red[t] = (t < DD) ? mu[t] * agw[DD + t] : 0.f;
  __syncthreads();
  for (int s = 128; s > 0; s >>= 1) { if (t < s) red[t] += red[t + s]; __syncthreads(); }
  if (t == 0) bcst[0] = red[0] + agb[0];
  __syncthreads();
  float lgt = bcst[0];
  {
    const float* row = U + t * DD;
    float s = 0.f;
    #pragma unroll 8
    for (int d2 = 0; d2 < DD; ++d2) s += row[d2] * agw[d2];
    lgt += s;
  }
  red[t] = lgt;
  __syncthreads();
  for (int s = 128; s > 0; s >>= 1) { if (t < s) red[t] = fmaxf(red[t], red[t + s]); __syncthreads(); }
  float m = red[0];
  __syncthreads();
  float e = expf(lgt - m);
  red[t] = e;
  __syncthreads();
  for (int s = 128; s > 0; s >>= 1) { if (t < s) red[t] += red[t + s]; __syncthreads(); }
  float inv = 1.f / red[0];
  __syncthreads();
  lg[t] = e * inv;
  __syncthreads();
  if (t < DD) {
    float s = 0.f;
    for (int j = 0; j < NN; ++j) s += lg[j] * U[j * DD + t];
    r[g * DD + t] = s;
  }
}

__global__ void finalk(const float* __restrict__ r, float* __restrict__ out)
{
  const int t = threadIdx.x; // 128
  __shared__ float r0[DD], r1s[DD], r2s[DD];
  float a = r[t], b = r[DD + t];
  r0[t] = a * b; r1s[t] = a * a; r2s[t] = b * b;
  __syncthreads();
  for (int s = 64; s > 0; s >>= 1) {
    if (t < s) { r0[t] += r0[t + s]; r1s[t] += r1s[t + s]; r2s[t] += r2s[t + s]; }
    __syncthreads();
  }
  if (t == 0) {
    float den = fmaxf(sqrtf(r1s[0]) * sqrtf(r2s[0]), 1e-8f);
    out[0] = (r0[0] / den + 1.f) * 0.5f;
  }
}

extern "C" void kernel_launch(void* const* d_in, const int* in_sizes, int n_in,
                              void* d_out, int out_size, void* d_ws, size_t ws_size,
                              hipStream_t stream)
{
  (void)in_sizes; (void)n_in; (void)out_size; (void)ws_size;
  const float* g1   = (const float*)d_in[0];
  const float* g2   = (const float*)d_in[1];
  const float* new1 = (const float*)d_in[2];
  const float* neb1 = (const float*)d_in[3];
  const float* new2 = (const float*)d_in[4];
  const float* neb2 = (const float*)d_in[5];
  const float* eew1 = (const float*)d_in[6];
  const float* eeb1 = (const float*)d_in[7];
  const float* eew2 = (const float*)d_in[8];
  const float* eeb2 = (const float*)d_in[9];
  const float* prw1 = (const float*)d_in[10];
  const float* prb1 = (const float*)d_in[11];
  const float* prw2 = (const float*)d_in[12];
  const float* prb2 = (const float*)d_in[13];
  const float* upw  = (const float*)d_in[14];
  const float* upb  = (const float*)d_in[15];
  const float* agw  = (const float*)d_in[16];
  const float* agb  = (const float*)d_in[17];
  float* W = (float*)d_ws;
  float* out = (float*)d_out;

  float* H1    = W + WS_H1;
  float* emb   = W + WS_EMB;
  float* Aev   = W + WS_AE;
  float* Cev   = W + WS_CE;
  float* Ppv   = W + WS_PP;
  float* Qmv   = W + WS_QM;
  float* Sv    = W + WS_S;
  float* intra = W + WS_INTRA;
  float* crs   = W + WS_CROSS;
  float* updv  = W + WS_UPD;
  float* rv    = W + WS_R;
  float* pb    = W + WS_PB;
  float* Sb    = W + WS_SB;

  dim3 gA(NN, 1, 2);

  // pb = pr_b1 + ee_b2 @ WE
  prep_pbk<<<2, 256, 0, stream>>>(eeb2, prw1, prb1, pb);
  // H1 = relu(x @ ne_w1 + ne_b1)
  rowgemm<<<gA, 256, 0, stream>>>(g1, g2, DD, new1, HH, neb1, nullptr, 0,
                                  H1, NN * HH, HH, HH, DD, 1, 1.f);
  // emb = H1 @ ne_w2 + ne_b2
  rowgemm<<<gA, 256, 0, stream>>>(H1, H1 + NN * HH, HH, new2, DD, neb2, nullptr, 0,
                                  emb, NN * DD, DD, DD, HH, 0, 1.f);
  // Ae = x @ ee_w1[0:128] + ee_b1 + ee_w1[128+i]
  rowgemm<<<gA, 256, 0, stream>>>(g1, g2, DD, eew1, HH, eeb1, eew1 + DD * HH, HH,
                                  Aev, NN * HH, HH, HH, DD, 0, 1.f);
  // Ce = x @ ee_w1[384:512] + ee_w1[512+j]
  rowgemm<<<gA, 256, 0, stream>>>(g1, g2, DD, eew1 + (DD + NN) * HH, HH, nullptr,
                                  eew1 + (2 * DD + NN) * HH, HH,
                                  Cev, NN * HH, HH, HH, DD, 0, 1.f);
  // Pp = x @ pr_w1[0:128] + pb
  rowgemm<<<gA, 256, 0, stream>>>(g1, g2, DD, prw1, HH, pb, nullptr, 0,
                                  Ppv, NN * HH, HH, HH, DD, 0, 1.f);
  // Qm = x @ pr_w1[128:256]
  rowgemm<<<gA, 256, 0, stream>>>(g1, g2, DD, prw1 + DD * HH, HH, nullptr, nullptr, 0,
                                  Qmv, NN * HH, HH, HH, DD, 0, 1.f);
  // heavy fused per-edge pipeline -> S
  heavyk<<<dim3(NN / 2, 1, 2), 256, 0, stream>>>(Aev, Cev, Ppv, Qmv, eew2, prw1, Sv);
  // intra = (S/N) @ pr_w2 + pr_b2
  rowgemm<<<gA, 256, 0, stream>>>(Sv, Sv + NN * HH, HH, prw2, DD, prb2, nullptr, 0,
                                  intra, NN * DD, DD, DD, HH, 0, 1.f / NN);
  // interact
  colsumk<<<2, DD, 0, stream>>>(emb, Sb);
  interactk<<<dim3(NN, 2), DD, 0, stream>>>(emb, Sb, crs);
  // update
  updk<<<dim3(NN, 1, 2), DD, 0, stream>>>(emb, intra, crs, upw, upb, updv);
  // aggregate + final cosine
  aggregatek<<<2, 256, 0, stream>>>(updv, agw, agb, rv);
  finalk<<<1, DD, 0, stream>>>(rv, out);
}

// Round 2
// 353.813 us; speedup vs baseline: 1.8430x; 1.8430x over previous
//
#include <hip/hip_runtime.h>
#include <math.h>

#define NN 256
#define DD 128
#define HH 512

// ---------------- workspace layout (float offsets) ----------------
#define WS_H1    0         // [2][256][512]
#define WS_EMB   262144    // [2][256][128]
#define WS_AE    327680    // [2][256][512]
#define WS_CE    589824    // [2][256][512]
#define WS_PP    851968    // [2][256][512]
#define WS_QM    1114112   // [2][256][512]
#define WS_S     1376256   // [2][256][512]
#define WS_INTRA 1638400   // [2][256][128]
#define WS_CROSS 1703936   // [2][256][128]
#define WS_UPD   1769472   // [2][256][128]
#define WS_R     1835008   // [2][128]
#define WS_PB    1835264   // [512]
#define WS_SB    1835776   // [2][128]
#define WS_W2F   1836032   // 65536 bf16 = 32768 floats (W2^T frag-linear)
#define WS_WEF   1868800   // 65536 bf16 = 32768 floats (WE^T frag-linear)
// total 1901568 floats ~= 7.3 MB

typedef __attribute__((ext_vector_type(8))) short short8v;
typedef __attribute__((ext_vector_type(4))) float f32x4;

__device__ __forceinline__ short f2b(float x) {
  union { float f; unsigned u; } c; c.f = x;
  unsigned r = c.u + 0x7fffu + ((c.u >> 16) & 1u);   // RNE
  return (short)(r >> 16);
}

// C[g][row][c] = act( ascale*A_g[row,:] @ B + cb[c] + rowm[row,c] )
__global__ void rowgemm(const float* __restrict__ A0, const float* __restrict__ A1, int lda,
                        const float* __restrict__ B, int ldb,
                        const float* __restrict__ cb,
                        const float* __restrict__ rowm, int ldr,
                        float* __restrict__ C, int cstride, int ldc,
                        int Nc, int K, int relu, float ascale)
{
  __shared__ float Ar[HH];
  const int row = blockIdx.x;
  const int g = blockIdx.z;
  const float* A = g ? A1 : A0;
  for (int k = threadIdx.x; k < K; k += 256) Ar[k] = A[row * lda + k] * ascale;
  __syncthreads();
  for (int c = threadIdx.x; c < Nc; c += 256) {
    float acc = cb ? cb[c] : 0.f;
    if (rowm) acc += rowm[row * ldr + c];
    #pragma unroll 8
    for (int k = 0; k < K; ++k) acc = fmaf(Ar[k], B[k * ldb + c], acc);
    if (relu) acc = fmaxf(acc, 0.f);
    C[g * cstride + row * ldc + c] = acc;
  }
}

// pb[h] = pr_b1[h] + sum_d ee_b2[d] * WE[d][h]   (WE = pr_w1 rows 256..383)
__global__ void prep_pbk(const float* __restrict__ eeb2, const float* __restrict__ prw1,
                         const float* __restrict__ prb1, float* __restrict__ pb)
{
  const int h = blockIdx.x * 256 + threadIdx.x;
  float s = prb1[h];
  for (int d = 0; d < DD; ++d) s += eeb2[d] * prw1[(2 * DD + d) * HH + h];
  pb[h] = s;
}

// ---- weight pre-swizzle into MFMA A-fragment-linear bf16 ----
// A-frag (16x16x32): lane l: row m = l&15, k = (l>>4)*8 + t
// W2f frag f = kc*8+ct : value = W2[kc*32 + (l>>4)*8 + t][ct*16 + (l&15)]
__global__ void swz_w2(const float* __restrict__ W2, short* __restrict__ W2f)
{
  const int f = blockIdx.x;        // 0..127
  const int l = threadIdx.x;       // 0..63
  const int kc = f >> 3, ct = f & 7;
  const int kbase = kc * 32 + (l >> 4) * 8;
  const int c = ct * 16 + (l & 15);
  short8v v;
  #pragma unroll
  for (int t = 0; t < 8; ++t) v[t] = f2b(W2[(kbase + t) * DD + c]);
  *(short8v*)&W2f[(f * 64 + l) * 8] = v;
}

// WEf frag f = kc2*32+htg : value = WE[kc2*32+(l>>4)*8+t][htg*16+(l&15)],
// WE[c][h] = pr_w1[(256+c)*512 + h]
__global__ void swz_we(const float* __restrict__ prw1, short* __restrict__ WEf)
{
  const int f = blockIdx.x;        // 0..127
  const int l = threadIdx.x;
  const int kc2 = f >> 5, htg = f & 31;
  const int cbase = kc2 * 32 + (l >> 4) * 8;
  const int h = htg * 16 + (l & 15);
  short8v v;
  #pragma unroll
  for (int t = 0; t < 8; ++t) v[t] = f2b(prw1[(2 * DD + cbase + t) * HH + h]);
  *(short8v*)&WEf[(f * 64 + l) * 8] = v;
}

// ---------------- fused heavy edge kernel (MFMA) ----------------
// block: 1 i x 256 j, 4 waves, wave w owns e in [64w,64w+64)
// stage1: U^T[c][e] = sum_k W2[k][c] * relu(Ae[k]+Ce[j][k])     (D1 = A(W2^T) B(T^T))
// stage2: G^T[h][e] = sum_c WE[c][h] * U[e][c]                  (D2 = A(WE^T) B(U^T))
// S[i][h] = sum_e relu(Pp[h] + Qm[j][h] + G^T[h][e])
__global__ __launch_bounds__(256, 2)
void heavy_mfma(const float* __restrict__ AeG, const float* __restrict__ CeG,
                const float* __restrict__ PpG, const float* __restrict__ QmG,
                const short* __restrict__ W2f, const short* __restrict__ WEf,
                float* __restrict__ SG)
{
  __shared__ short Ut[NN * DD];          // 64 KB, XOR-swizzled on 8B blocks
  __shared__ float AeL[HH], PpL[HH];     // 2 KB each
  __shared__ float Sp[4][HH];            // 8 KB
  const int g = blockIdx.z;
  const int i = blockIdx.x;
  const int tid = threadIdx.x;
  const float* Ae = AeG + (g * NN + i) * HH;
  const float* Pp = PpG + (g * NN + i) * HH;
  const float* Ce = CeG + g * NN * HH;
  const float* Qm = QmG + g * NN * HH;

  for (int k = tid; k < HH; k += 256) { AeL[k] = Ae[k]; PpL[k] = Pp[k]; }
  __syncthreads();

  const int w = tid >> 6;
  const int l = tid & 63;
  const int low = l & 15, q = l >> 4;
  const int ebase = w * 64;
  const int xsw = (low & 7) << 1;        // swizzle term (e&7)*2, e&7 == low&7

  // ---------------- stage 1 ----------------
  {
    f32x4 acc[8][4];
    #pragma unroll
    for (int ct = 0; ct < 8; ++ct)
      #pragma unroll
      for (int et = 0; et < 4; ++et) acc[ct][et] = (f32x4){0.f, 0.f, 0.f, 0.f};

    for (int kc = 0; kc < 16; ++kc) {
      const int k0 = kc * 32 + q * 8;
      const float4 a0 = *(const float4*)&AeL[k0];
      const float4 a1 = *(const float4*)&AeL[k0 + 4];
      short8v bfr[4];
      #pragma unroll
      for (int et = 0; et < 4; ++et) {
        const int j = ebase + et * 16 + low;
        const float4 c0 = *(const float4*)&Ce[j * HH + k0];
        const float4 c1 = *(const float4*)&Ce[j * HH + k0 + 4];
        short8v v;
        v[0] = f2b(fmaxf(a0.x + c0.x, 0.f));
        v[1] = f2b(fmaxf(a0.y + c0.y, 0.f));
        v[2] = f2b(fmaxf(a0.z + c0.z, 0.f));
        v[3] = f2b(fmaxf(a0.w + c0.w, 0.f));
        v[4] = f2b(fmaxf(a1.x + c1.x, 0.f));
        v[5] = f2b(fmaxf(a1.y + c1.y, 0.f));
        v[6] = f2b(fmaxf(a1.z + c1.z, 0.f));
        v[7] = f2b(fmaxf(a1.w + c1.w, 0.f));
        bfr[et] = v;
      }
      #pragma unroll
      for (int ct = 0; ct < 8; ++ct) {
        const short8v af = *(const short8v*)&W2f[((kc * 8 + ct) * 64 + l) * 8];
        #pragma unroll
        for (int et = 0; et < 4; ++et)
          acc[ct][et] = __builtin_amdgcn_mfma_f32_16x16x32_bf16(af, bfr[et], acc[ct][et], 0, 0, 0);
      }
    }
    // D1^T C-layout: lane holds c = ct*16 + q*4 + r (r=0..3), e = ebase + et*16 + low
    #pragma unroll
    for (int ct = 0; ct < 8; ++ct)
      #pragma unroll
      for (int et = 0; et < 4; ++et) {
        const int e = ebase + et * 16 + low;
        const int cb = ct * 4 + q;
        short4 pk;
        pk.x = f2b(acc[ct][et][0]);
        pk.y = f2b(acc[ct][et][1]);
        pk.z = f2b(acc[ct][et][2]);
        pk.w = f2b(acc[ct][et][3]);
        *(short4*)&Ut[e * DD + ((cb ^ xsw) << 2)] = pk;
      }
  }
  __syncthreads();

  // ---------------- stage 2 ----------------
  for (int hc = 0; hc < 4; ++hc) {
    f32x4 acc2[8][4];
    #pragma unroll
    for (int ht = 0; ht < 8; ++ht)
      #pragma unroll
      for (int et = 0; et < 4; ++et) acc2[ht][et] = (f32x4){0.f, 0.f, 0.f, 0.f};

    #pragma unroll
    for (int kc2 = 0; kc2 < 4; ++kc2) {
      short8v bfr[4];
      #pragma unroll
      for (int et = 0; et < 4; ++et) {
        const int e = ebase + et * 16 + low;
        const int cb0 = kc2 * 8 + q * 2;
        bfr[et] = *(const short8v*)&Ut[e * DD + ((cb0 ^ xsw) << 2)];
      }
      #pragma unroll
      for (int ht = 0; ht < 8; ++ht) {
        const short8v af = *(const short8v*)&WEf[((kc2 * 32 + hc * 8 + ht) * 64 + l) * 8];
        #pragma unroll
        for (int et = 0; et < 4; ++et)
          acc2[ht][et] = __builtin_amdgcn_mfma_f32_16x16x32_bf16(af, bfr[et], acc2[ht][et], 0, 0, 0);
      }
    }
    // epilogue: relu(Pp + Qm + G), per-lane partial over e, cross-lane reduce
    float part[8][4];
    #pragma unroll
    for (int ht = 0; ht < 8; ++ht)
      #pragma unroll
      for (int r = 0; r < 4; ++r) part[ht][r] = 0.f;

    #pragma unroll
    for (int ht = 0; ht < 8; ++ht) {
      const int h0 = hc * 128 + ht * 16 + q * 4;
      const float4 pp = *(const float4*)&PpL[h0];
      #pragma unroll
      for (int et = 0; et < 4; ++et) {
        const int j = ebase + et * 16 + low;
        const float4 qm = *(const float4*)&Qm[j * HH + h0];
        part[ht][0] += fmaxf(pp.x + qm.x + acc2[ht][et][0], 0.f);
        part[ht][1] += fmaxf(pp.y + qm.y + acc2[ht][et][1], 0.f);
        part[ht][2] += fmaxf(pp.z + qm.z + acc2[ht][et][2], 0.f);
        part[ht][3] += fmaxf(pp.w + qm.w + acc2[ht][et][3], 0.f);
      }
    }
    #pragma unroll
    for (int ht = 0; ht < 8; ++ht)
      #pragma unroll
      for (int r = 0; r < 4; ++r) {
        float v = part[ht][r];
        v += __shfl_xor(v, 1);
        v += __shfl_xor(v, 2);
        v += __shfl_xor(v, 4);
        v += __shfl_xor(v, 8);
        if (low == 0) Sp[w][hc * 128 + ht * 16 + q * 4 + r] = v;
      }
  }
  __syncthreads();

  float* S = SG + (g * NN + i) * HH;
  for (int h = tid; h < HH; h += 256)
    S[h] = Sp[0][h] + Sp[1][h] + Sp[2][h] + Sp[3][h];
}

// Sb[g][d] = sum_j emb[g][j][d]
__global__ void colsumk(const float* __restrict__ embG, float* __restrict__ Sb)
{
  const int g = blockIdx.x, d = threadIdx.x;
  const float* E = embG + g * NN * DD;
  float s = 0.f;
  for (int j = 0; j < NN; ++j) s += E[j * DD + d];
  Sb[g * DD + d] = s;
}

// cross[dir][i][d] = (sum_j b[j,d]*exp(a[i,d]*b[j,d])) / (N * a[i,d] * Sb_b[d])
__global__ void interactk(const float* __restrict__ embG, const float* __restrict__ Sb,
                          float* __restrict__ cross)
{
  const int i = blockIdx.x, dir = blockIdx.y, d = threadIdx.x;
  const float* A = embG + dir * NN * DD;
  const float* B = embG + (1 - dir) * NN * DD;
  float av = A[i * DD + d];
  float acc = 0.f;
  for (int j = 0; j < NN; ++j) {
    float bv = B[j * DD + d];
    acc += bv * expf(av * bv);
  }
  float den = (float)NN * av * Sb[(1 - dir) * DD + d];
  cross[dir * NN * DD + i * DD + d] = acc / den;
}

// upd[g][i][:] = [l2n(emb), l2n(intra), l2n(cross)] @ up_w + up_b
__global__ void updk(const float* __restrict__ emb, const float* __restrict__ intra,
                     const float* __restrict__ cross, const float* __restrict__ upw,
                     const float* __restrict__ upb, float* __restrict__ upd)
{
  const int i = blockIdx.x, g = blockIdx.z, d = threadIdx.x; // 128 threads
  __shared__ float v[3 * DD];
  __shared__ float red[DD];
  const int base = g * NN * DD + i * DD;
  {
    float x = emb[base + d];
    red[d] = x * x; __syncthreads();
    for (int s = 64; s > 0; s >>= 1) { if (d < s) red[d] += red[d + s]; __syncthreads(); }
    v[d] = x / fmaxf(sqrtf(red[0]), 1e-12f);
    __syncthreads();
  }
  {
    float x = intra[base + d];
    red[d] = x * x; __syncthreads();
    for (int s = 64; s > 0; s >>= 1) { if (d < s) red[d] += red[d + s]; __syncthreads(); }
    v[DD + d] = x / fmaxf(sqrtf(red[0]), 1e-12f);
    __syncthreads();
  }
  {
    float x = cross[base + d];
    red[d] = x * x; __syncthreads();
    for (int s = 64; s > 0; s >>= 1) { if (d < s) red[d] += red[d + s]; __syncthreads(); }
    v[2 * DD + d] = x / fmaxf(sqrtf(red[0]), 1e-12f);
    __syncthreads();
  }
  float acc = upb[d];
  #pragma unroll 8
  for (int k = 0; k < 3 * DD; ++k) acc = fmaf(v[k], upw[k * DD + d], acc);
  upd[base + d] = acc;
}

// r[g][:] = sum_i softmax_i(feats@ag_w+ag_b) * upd[g][i][:]
__global__ void aggregatek(const float* __restrict__ updG, const float* __restrict__ agw,
                           const float* __restrict__ agb, float* __restrict__ r)
{
  const int g = blockIdx.x;
  const int t = threadIdx.x; // 256
  const float* U = updG + g * NN * DD;
  __shared__ float mu[DD], lg[NN], red[NN], bcst[1];
  if (t < DD) {
    float s = 0.f;
    for (int j = 0; j < NN; ++j) s += U[j * DD + t];
    mu[t] = s * (1.f / NN);
  }
  __syncthreads();
  red[t] = (t < DD) ? mu[t] * agw[DD + t] : 0.f;
  __syncthreads();
  for (int s = 128; s > 0; s >>= 1) { if (t < s) red[t] += red[t + s]; __syncthreads(); }
  if (t == 0) bcst[0] = red[0] + agb[0];
  __syncthreads();
  float lgt = bcst[0];
  {
    const float* row = U + t * DD;
    float s = 0.f;
    #pragma unroll 8
    for (int d2 = 0; d2 < DD; ++d2) s += row[d2] * agw[d2];
    lgt += s;
  }
  red[t] = lgt;
  __syncthreads();
  for (int s = 128; s > 0; s >>= 1) { if (t < s) red[t] = fmaxf(red[t], red[t + s]); __syncthreads(); }
  float m = red[0];
  __syncthreads();
  float e = expf(lgt - m);
  red[t] = e;
  __syncthreads();
  for (int s = 128; s > 0; s >>= 1) { if (t < s) red[t] += red[t + s]; __syncthreads(); }
  float inv = 1.f / red[0];
  __syncthreads();
  lg[t] = e * inv;
  __syncthreads();
  if (t < DD) {
    float s = 0.f;
    for (int j = 0; j < NN; ++j) s += lg[j] * U[j * DD + t];
    r[g * DD + t] = s;
  }
}

__global__ void finalk(const float* __restrict__ r, float* __restrict__ out)
{
  const int t = threadIdx.x; // 128
  __shared__ float r0[DD], r1s[DD], r2s[DD];
  float a = r[t], b = r[DD + t];
  r0[t] = a * b; r1s[t] = a * a; r2s[t] = b * b;
  __syncthreads();
  for (int s = 64; s > 0; s >>= 1) {
    if (t < s) { r0[t] += r0[t + s]; r1s[t] += r1s[t + s]; r2s[t] += r2s[t + s]; }
    __syncthreads();
  }
  if (t == 0) {
    float den = fmaxf(sqrtf(r1s[0]) * sqrtf(r2s[0]), 1e-8f);
    out[0] = (r0[0] / den + 1.f) * 0.5f;
  }
}

extern "C" void kernel_launch(void* const* d_in, const int* in_sizes, int n_in,
                              void* d_out, int out_size, void* d_ws, size_t ws_size,
                              hipStream_t stream)
{
  (void)in_sizes; (void)n_in; (void)out_size; (void)ws_size;
  const float* g1   = (const float*)d_in[0];
  const float* g2   = (const float*)d_in[1];
  const float* new1 = (const float*)d_in[2];
  const float* neb1 = (const float*)d_in[3];
  const float* new2 = (const float*)d_in[4];
  const float* neb2 = (const float*)d_in[5];
  const float* eew1 = (const float*)d_in[6];
  const float* eeb1 = (const float*)d_in[7];
  const float* eew2 = (const float*)d_in[8];
  const float* eeb2 = (const float*)d_in[9];
  const float* prw1 = (const float*)d_in[10];
  const float* prb1 = (const float*)d_in[11];
  const float* prw2 = (const float*)d_in[12];
  const float* prb2 = (const float*)d_in[13];
  const float* upw  = (const float*)d_in[14];
  const float* upb  = (const float*)d_in[15];
  const float* agw  = (const float*)d_in[16];
  const float* agb  = (const float*)d_in[17];
  float* W = (float*)d_ws;
  float* out = (float*)d_out;

  float* H1    = W + WS_H1;
  float* emb   = W + WS_EMB;
  float* Aev   = W + WS_AE;
  float* Cev   = W + WS_CE;
  float* Ppv   = W + WS_PP;
  float* Qmv   = W + WS_QM;
  float* Sv    = W + WS_S;
  float* intra = W + WS_INTRA;
  float* crs   = W + WS_CROSS;
  float* updv  = W + WS_UPD;
  float* rv    = W + WS_R;
  float* pb    = W + WS_PB;
  float* Sb    = W + WS_SB;
  short* W2f   = (short*)(W + WS_W2F);
  short* WEf   = (short*)(W + WS_WEF);

  dim3 gA(NN, 1, 2);

  // pb = pr_b1 + ee_b2 @ WE
  prep_pbk<<<2, 256, 0, stream>>>(eeb2, prw1, prb1, pb);
  // pre-swizzle weights into MFMA fragment-linear bf16
  swz_w2<<<128, 64, 0, stream>>>(eew2, W2f);
  swz_we<<<128, 64, 0, stream>>>(prw1, WEf);
  // H1 = relu(x @ ne_w1 + ne_b1)
  rowgemm<<<gA, 256, 0, stream>>>(g1, g2, DD, new1, HH, neb1, nullptr, 0,
                                  H1, NN * HH, HH, HH, DD, 1, 1.f);
  // emb = H1 @ ne_w2 + ne_b2
  rowgemm<<<gA, 256, 0, stream>>>(H1, H1 + NN * HH, HH, new2, DD, neb2, nullptr, 0,
                                  emb, NN * DD, DD, DD, HH, 0, 1.f);
  // Ae = x @ ee_w1[0:128] + ee_b1 + ee_w1[128+i]
  rowgemm<<<gA, 256, 0, stream>>>(g1, g2, DD, eew1, HH, eeb1, eew1 + DD * HH, HH,
                                  Aev, NN * HH, HH, HH, DD, 0, 1.f);
  // Ce = x @ ee_w1[384:512] + ee_w1[512+j]
  rowgemm<<<gA, 256, 0, stream>>>(g1, g2, DD, eew1 + (DD + NN) * HH, HH, nullptr,
                                  eew1 + (2 * DD + NN) * HH, HH,
                                  Cev, NN * HH, HH, HH, DD, 0, 1.f);
  // Pp = x @ pr_w1[0:128] + pb
  rowgemm<<<gA, 256, 0, stream>>>(g1, g2, DD, prw1, HH, pb, nullptr, 0,
                                  Ppv, NN * HH, HH, HH, DD, 0, 1.f);
  // Qm = x @ pr_w1[128:256]
  rowgemm<<<gA, 256, 0, stream>>>(g1, g2, DD, prw1 + DD * HH, HH, nullptr, nullptr, 0,
                                  Qmv, NN * HH, HH, HH, DD, 0, 1.f);
  // heavy fused per-edge pipeline (MFMA) -> S
  heavy_mfma<<<dim3(NN, 1, 2), 256, 0, stream>>>(Aev, Cev, Ppv, Qmv, W2f, WEf, Sv);
  // intra = (S/N) @ pr_w2 + pr_b2
  rowgemm<<<gA, 256, 0, stream>>>(Sv, Sv + NN * HH, HH, prw2, DD, prb2, nullptr, 0,
                                  intra, NN * DD, DD, DD, HH, 0, 1.f / NN);
  // interact
  colsumk<<<2, DD, 0, stream>>>(emb, Sb);
  interactk<<<dim3(NN, 2), DD, 0, stream>>>(emb, Sb, crs);
  // update
  updk<<<dim3(NN, 1, 2), DD, 0, stream>>>(emb, intra, crs, upw, upb, updv);
  // aggregate + final cosine
  aggregatek<<<2, 256, 0, stream>>>(updv, agw, agb, rv);
  finalk<<<1, DD, 0, stream>>>(rv, out);
}

// Round 3
// 272.769 us; speedup vs baseline: 2.3906x; 1.2971x over previous
//
#include <hip/hip_runtime.h>
#include <math.h>

#define NN 256
#define DD 128
#define HH 512

// ---------------- workspace layout (float offsets) ----------------
#define WS_XW    0         // [2][256][2048] bf16 panel: Ae|Ce|Pp|Qm  (524288 f)
#define WS_XEXT  524288    // [512][416] f32
#define WS_W4F   737280    // 1664 frags *512 shorts = 425984 f
#define WS_H1    737280    // [512][512] f32, aliases W4F (dead after big4)
#define WS_W2F   1163264   // 128 frags (32768 f)
#define WS_WEF   1196032
#define WS_W1NF  1228800
#define WS_W2NF  1261568
#define WS_PW2F  1294336
#define WS_EMB   1327104   // [2][256][128] f32
#define WS_S     1392640   // [2][256][512] f32
#define WS_INTRA 1654784
#define WS_CROSS 1720320
#define WS_UPD   1785856
#define WS_PB    1851392   // [512]
// total 1851904 floats ~= 7.06 MB

typedef __attribute__((ext_vector_type(8))) short short8v;
typedef __attribute__((ext_vector_type(4))) float f32x4;

__device__ __forceinline__ short f2b(float x) {
  union { float f; unsigned u; } c; c.f = x;
  unsigned r = c.u + 0x7fffu + ((c.u >> 16) & 1u);   // RNE
  return (short)(r >> 16);
}
__device__ __forceinline__ float b2f(short s) {
  union { unsigned u; float f; } c; c.u = ((unsigned)(unsigned short)s) << 16;
  return c.f;
}

// pb[h] = pr_b1[h] + sum_d ee_b2[d] * WE[d][h]   (WE = pr_w1 rows 256..383)
__global__ void prep_pbk(const float* __restrict__ eeb2, const float* __restrict__ prw1,
                         const float* __restrict__ prb1, float* __restrict__ pb)
{
  const int h = blockIdx.x * 256 + threadIdx.x;
  float s = prb1[h];
  for (int d = 0; d < DD; ++d) s += eeb2[d] * prw1[(2 * DD + d) * HH + h];
  pb[h] = s;
}

// Xext[m][0:128]=x_g[i], [128:384]=onehot(i), [384]=1, [385:416)=0
__global__ void xextk(const float* __restrict__ g1, const float* __restrict__ g2,
                      float* __restrict__ Xe)
{
  const int m = blockIdx.x;
  const int g = m >> 8, i = m & 255;
  const float* src = (g ? g2 : g1) + i * DD;
  float* dst = Xe + m * 416;
  for (int c = threadIdx.x; c < 416; c += 256) {
    float v;
    if (c < 128) v = src[c];
    else if (c < 384) v = (c - 128 == i) ? 1.f : 0.f;
    else v = (c == 384) ? 1.f : 0.f;
    dst[c] = v;
  }
}

// batched frag-linear swizzle of the five 128-frag weights (A-operand layout)
__global__ void swz5(const float* __restrict__ eew2, const float* __restrict__ prw1,
                     const float* __restrict__ new1, const float* __restrict__ new2,
                     const float* __restrict__ prw2, float* __restrict__ Wb)
{
  const int f = blockIdx.x, l = threadIdx.x;
  const int low = l & 15, q = l >> 4;
  const float* src; int ld, nt; short* dst;
  switch (blockIdx.y) {
    case 0:  src = eew2;              ld = 128; nt = 8;  dst = (short*)(Wb + WS_W2F);  break;
    case 1:  src = prw1 + 2*DD*HH;    ld = 512; nt = 32; dst = (short*)(Wb + WS_WEF);  break;
    case 2:  src = new1;              ld = 512; nt = 32; dst = (short*)(Wb + WS_W1NF); break;
    case 3:  src = new2;              ld = 128; nt = 8;  dst = (short*)(Wb + WS_W2NF); break;
    default: src = prw2;              ld = 128; nt = 8;  dst = (short*)(Wb + WS_PW2F); break;
  }
  const int kcI = f / nt, ntI = f % nt;
  const int n = ntI * 16 + low;
  const int kb = kcI * 32 + q * 8;
  short8v v;
  #pragma unroll
  for (int t = 0; t < 8; ++t) v[t] = f2b(src[(kb + t) * ld + n]);
  *(short8v*)&dst[(f * 64 + l) * 8] = v;
}

// assembled big-4 weight (K=416, N=2048): slices Ae|Ce|Pp|Qm with one-hot rows,
// eeb1 / pb folded in at k=384
__global__ void swz_w4(const float* __restrict__ eew1, const float* __restrict__ prw1,
                       const float* __restrict__ eeb1, const float* __restrict__ pb,
                       short* __restrict__ W4f)
{
  const int f = blockIdx.x, l = threadIdx.x;
  const int low = l & 15, q = l >> 4;
  const int kcI = f >> 7, ntI = f & 127;
  const int n = ntI * 16 + low, slice = n >> 9, np = n & 511;
  const int kb = kcI * 32 + q * 8;
  short8v v;
  #pragma unroll
  for (int t = 0; t < 8; ++t) {
    const int k = kb + t;
    float val = 0.f;
    if (k < 384) {
      if (slice == 0)      val = eew1[k * HH + np];
      else if (slice == 1) val = eew1[(384 + k) * HH + np];
      else if (slice == 2) val = (k < 128) ? prw1[k * HH + np] : 0.f;
      else                 val = (k < 128) ? prw1[(128 + k) * HH + np] : 0.f;
    } else if (k == 384) {
      if (slice == 0)      val = eeb1[np];
      else if (slice == 2) val = pb[np];
    }
    v[t] = f2b(val);
  }
  *(short8v*)&W4f[(f * 64 + l) * 8] = v;
}

// ---------------- generic transposed MFMA GEMM ----------------
// Out[m][n] = act( bscale*Bsrc[m,:] @ W + bias[n] ), W given as frag-linear A.
// block: 64 m x (4 waves * FT*16 n); computed as D^T = A(W^T) * B(Bsrc^T).
template<int FT, int OBF16, int ORELU>
__global__ __launch_bounds__(256, 2)
void gemmT(const float* __restrict__ Bsrc, int ldb, float bscale,
           const short* __restrict__ Af, int ntTot, int kcN,
           const float* __restrict__ bias,
           float* __restrict__ OutF, int ldo)
{
  const int tid = threadIdx.x;
  const int w = tid >> 6, l = tid & 63, low = l & 15, q = l >> 4;
  const int mb = blockIdx.x * 64;
  const int nb = (blockIdx.y * 4 + w) * (FT * 16);
  f32x4 acc[FT][4];
  #pragma unroll
  for (int ft = 0; ft < FT; ++ft)
    #pragma unroll
    for (int et = 0; et < 4; ++et) acc[ft][et] = (f32x4){0.f, 0.f, 0.f, 0.f};

  for (int kc = 0; kc < kcN; ++kc) {
    const int k0 = kc * 32 + q * 8;
    short8v bfr[4];
    #pragma unroll
    for (int et = 0; et < 4; ++et) {
      const int m = mb + et * 16 + low;
      const float* p = Bsrc + m * ldb + k0;
      const float4 b0 = *(const float4*)p;
      const float4 b1 = *(const float4*)(p + 4);
      short8v v;
      v[0] = f2b(b0.x * bscale); v[1] = f2b(b0.y * bscale);
      v[2] = f2b(b0.z * bscale); v[3] = f2b(b0.w * bscale);
      v[4] = f2b(b1.x * bscale); v[5] = f2b(b1.y * bscale);
      v[6] = f2b(b1.z * bscale); v[7] = f2b(b1.w * bscale);
      bfr[et] = v;
    }
    #pragma unroll
    for (int ft = 0; ft < FT; ++ft) {
      const int ng = (nb >> 4) + ft;
      const short8v af = *(const short8v*)&Af[((kc * ntTot + ng) * 64 + l) * 8];
      #pragma unroll
      for (int et = 0; et < 4; ++et)
        acc[ft][et] = __builtin_amdgcn_mfma_f32_16x16x32_bf16(af, bfr[et], acc[ft][et], 0, 0, 0);
    }
  }
  #pragma unroll
  for (int ft = 0; ft < FT; ++ft) {
    const int n0 = nb + ft * 16 + q * 4;
    float4 bs = make_float4(0.f, 0.f, 0.f, 0.f);
    if (bias) bs = *(const float4*)&bias[n0];
    #pragma unroll
    for (int et = 0; et < 4; ++et) {
      const int m = mb + et * 16 + low;
      float vx = acc[ft][et][0] + bs.x;
      float vy = acc[ft][et][1] + bs.y;
      float vz = acc[ft][et][2] + bs.z;
      float vw = acc[ft][et][3] + bs.w;
      if (ORELU) {
        vx = fmaxf(vx, 0.f); vy = fmaxf(vy, 0.f);
        vz = fmaxf(vz, 0.f); vw = fmaxf(vw, 0.f);
      }
      if (OBF16) {
        short4 pk;
        pk.x = f2b(vx); pk.y = f2b(vy); pk.z = f2b(vz); pk.w = f2b(vw);
        *(short4*)((short*)OutF + (size_t)m * ldo + n0) = pk;
      } else {
        *(float4*)&OutF[(size_t)m * ldo + n0] = make_float4(vx, vy, vz, vw);
      }
    }
  }
}

// ---------------- fused heavy edge kernel (MFMA, 8 waves, no spills) --------
// XW row layout per (g,node): [Ae(512) | Ce(512) | Pp(512) | Qm(512)] bf16.
// block: 1 i x 256 j; wave w owns e in [32w, 32w+32).
__global__ __launch_bounds__(512, 2)
void heavy_mfma(const short* __restrict__ XW, const short* __restrict__ W2f,
                const short* __restrict__ WEf, float* __restrict__ SG)
{
  __shared__ short Ut[NN * DD];          // 64 KB, XOR-swizzled 8B blocks
  __shared__ float AeL[HH], PpL[HH];     // 4 KB
  __shared__ float Sp[8][HH];            // 16 KB
  const int g = blockIdx.z, i = blockIdx.x, tid = threadIdx.x;
  const short* Xg = XW + (size_t)g * NN * 2048;
  const short* rowI = Xg + (size_t)i * 2048;
  AeL[tid] = b2f(rowI[tid]);
  PpL[tid] = b2f(rowI[1024 + tid]);
  __syncthreads();

  const int w = tid >> 6, l = tid & 63, low = l & 15, q = l >> 4;
  const int ebase = w << 5;
  const int xsw = (low & 7) << 1;

  // ---------- stage 1: Ut[e][c] = bf16( sum_k relu(Ae[k]+Ce[j][k]) * W2[k][c] ) ----------
  {
    f32x4 acc[8][2];
    #pragma unroll
    for (int ct = 0; ct < 8; ++ct) {
      acc[ct][0] = (f32x4){0.f, 0.f, 0.f, 0.f};
      acc[ct][1] = (f32x4){0.f, 0.f, 0.f, 0.f};
    }
    for (int kc = 0; kc < 16; ++kc) {
      const int k0 = kc * 32 + q * 8;
      const float4 a0 = *(const float4*)&AeL[k0];
      const float4 a1 = *(const float4*)&AeL[k0 + 4];
      short8v bfr[2];
      #pragma unroll
      for (int et = 0; et < 2; ++et) {
        const int j = ebase + et * 16 + low;
        const short8v c = *(const short8v*)&Xg[(size_t)j * 2048 + 512 + k0];
        short8v v;
        v[0] = f2b(fmaxf(a0.x + b2f(c[0]), 0.f));
        v[1] = f2b(fmaxf(a0.y + b2f(c[1]), 0.f));
        v[2] = f2b(fmaxf(a0.z + b2f(c[2]), 0.f));
        v[3] = f2b(fmaxf(a0.w + b2f(c[3]), 0.f));
        v[4] = f2b(fmaxf(a1.x + b2f(c[4]), 0.f));
        v[5] = f2b(fmaxf(a1.y + b2f(c[5]), 0.f));
        v[6] = f2b(fmaxf(a1.z + b2f(c[6]), 0.f));
        v[7] = f2b(fmaxf(a1.w + b2f(c[7]), 0.f));
        bfr[et] = v;
      }
      #pragma unroll
      for (int ct = 0; ct < 8; ++ct) {
        const short8v af = *(const short8v*)&W2f[((kc * 8 + ct) * 64 + l) * 8];
        acc[ct][0] = __builtin_amdgcn_mfma_f32_16x16x32_bf16(af, bfr[0], acc[ct][0], 0, 0, 0);
        acc[ct][1] = __builtin_amdgcn_mfma_f32_16x16x32_bf16(af, bfr[1], acc[ct][1], 0, 0, 0);
      }
    }
    #pragma unroll
    for (int ct = 0; ct < 8; ++ct)
      #pragma unroll
      for (int et = 0; et < 2; ++et) {
        const int e = ebase + et * 16 + low;
        const int cb = ct * 4 + q;
        short4 pk;
        pk.x = f2b(acc[ct][et][0]); pk.y = f2b(acc[ct][et][1]);
        pk.z = f2b(acc[ct][et][2]); pk.w = f2b(acc[ct][et][3]);
        *(short4*)&Ut[e * DD + ((cb ^ xsw) << 2)] = pk;
      }
  }
  __syncthreads();

  // ---------- stage 2: G^T = WE^T * U^T; S accumulation ----------
  for (int hc = 0; hc < 4; ++hc) {
    f32x4 acc2[8][2];
    #pragma unroll
    for (int ht = 0; ht < 8; ++ht) {
      acc2[ht][0] = (f32x4){0.f, 0.f, 0.f, 0.f};
      acc2[ht][1] = (f32x4){0.f, 0.f, 0.f, 0.f};
    }
    #pragma unroll
    for (int kc2 = 0; kc2 < 4; ++kc2) {
      short8v bfr[2];
      #pragma unroll
      for (int et = 0; et < 2; ++et) {
        const int e = ebase + et * 16 + low;
        const int cb0 = kc2 * 8 + q * 2;
        bfr[et] = *(const short8v*)&Ut[e * DD + ((cb0 ^ xsw) << 2)];
      }
      #pragma unroll
      for (int ht = 0; ht < 8; ++ht) {
        const short8v af = *(const short8v*)&WEf[((kc2 * 32 + hc * 8 + ht) * 64 + l) * 8];
        acc2[ht][0] = __builtin_amdgcn_mfma_f32_16x16x32_bf16(af, bfr[0], acc2[ht][0], 0, 0, 0);
        acc2[ht][1] = __builtin_amdgcn_mfma_f32_16x16x32_bf16(af, bfr[1], acc2[ht][1], 0, 0, 0);
      }
    }
    float part[8][4];
    #pragma unroll
    for (int ht = 0; ht < 8; ++ht)
      #pragma unroll
      for (int r = 0; r < 4; ++r) part[ht][r] = 0.f;
    #pragma unroll
    for (int ht = 0; ht < 8; ++ht) {
      const int h0 = hc * 128 + ht * 16 + q * 4;
      const float4 pp = *(const float4*)&PpL[h0];
      #pragma unroll
      for (int et = 0; et < 2; ++et) {
        const int j = ebase + et * 16 + low;
        const short4 qm = *(const short4*)&Xg[(size_t)j * 2048 + 1536 + h0];
        part[ht][0] += fmaxf(pp.x + b2f(qm.x) + acc2[ht][et][0], 0.f);
        part[ht][1] += fmaxf(pp.y + b2f(qm.y) + acc2[ht][et][1], 0.f);
        part[ht][2] += fmaxf(pp.z + b2f(qm.z) + acc2[ht][et][2], 0.f);
        part[ht][3] += fmaxf(pp.w + b2f(qm.w) + acc2[ht][et][3], 0.f);
      }
    }
    #pragma unroll
    for (int ht = 0; ht < 8; ++ht)
      #pragma unroll
      for (int r = 0; r < 4; ++r) {
        float v = part[ht][r];
        v += __shfl_xor(v, 1);
        v += __shfl_xor(v, 2);
        v += __shfl_xor(v, 4);
        v += __shfl_xor(v, 8);
        if (low == 0) Sp[w][hc * 128 + ht * 16 + q * 4 + r] = v;
      }
  }
  __syncthreads();
  float s = 0.f;
  #pragma unroll
  for (int w2 = 0; w2 < 8; ++w2) s += Sp[w2][tid];
  SG[((size_t)g * NN + i) * HH + tid] = s;
}

// cross[dir][i][d] = (sum_j b*exp(a*b)) / (N * a * sum_j b)   (colsum folded)
__global__ void interactk(const float* __restrict__ embG, float* __restrict__ cross)
{
  const int i = blockIdx.x, dir = blockIdx.y, d = threadIdx.x;
  const float* A = embG + dir * NN * DD;
  const float* B = embG + (1 - dir) * NN * DD;
  const float av = A[i * DD + d];
  float accN = 0.f, accS = 0.f;
  for (int j = 0; j < NN; ++j) {
    float bv = B[j * DD + d];
    accN += bv * expf(av * bv);
    accS += bv;
  }
  cross[dir * NN * DD + i * DD + d] = accN / (256.f * av * accS);
}

// upd[g][i][:] = [l2n(emb), l2n(intra), l2n(cross)] @ up_w + up_b
__global__ void updk(const float* __restrict__ emb, const float* __restrict__ intra,
                     const float* __restrict__ cross, const float* __restrict__ upw,
                     const float* __restrict__ upb, float* __restrict__ upd)
{
  const int i = blockIdx.x, g = blockIdx.z, d = threadIdx.x; // 128 threads
  __shared__ float v[3 * DD];
  __shared__ float red[DD];
  const int base = g * NN * DD + i * DD;
  {
    float x = emb[base + d];
    red[d] = x * x; __syncthreads();
    for (int s = 64; s > 0; s >>= 1) { if (d < s) red[d] += red[d + s]; __syncthreads(); }
    v[d] = x / fmaxf(sqrtf(red[0]), 1e-12f);
    __syncthreads();
  }
  {
    float x = intra[base + d];
    red[d] = x * x; __syncthreads();
    for (int s = 64; s > 0; s >>= 1) { if (d < s) red[d] += red[d + s]; __syncthreads(); }
    v[DD + d] = x / fmaxf(sqrtf(red[0]), 1e-12f);
    __syncthreads();
  }
  {
    float x = cross[base + d];
    red[d] = x * x; __syncthreads();
    for (int s = 64; s > 0; s >>= 1) { if (d < s) red[d] += red[d + s]; __syncthreads(); }
    v[2 * DD + d] = x / fmaxf(sqrtf(red[0]), 1e-12f);
    __syncthreads();
  }
  float acc = upb[d];
  #pragma unroll 8
  for (int k = 0; k < 3 * DD; ++k) acc = fmaf(v[k], upw[k * DD + d], acc);
  upd[base + d] = acc;
}

// fused aggregate (both graphs) + final cosine; 1 block x 512 threads
__global__ void aggfinal(const float* __restrict__ updG, const float* __restrict__ agw,
                         const float* __restrict__ agb, float* __restrict__ out)
{
  __shared__ float mu[2][DD];
  __shared__ float red[512];
  __shared__ float sg[512];
  __shared__ float rr[2][DD];
  __shared__ float md[2];
  const int t = threadIdx.x, gh = t >> 8, tl = t & 255;
  const float* U = updG + gh * NN * DD;
  if (tl < DD) {
    float s = 0.f;
    for (int j = 0; j < NN; ++j) s += U[j * DD + tl];
    mu[gh][tl] = s * (1.f / NN);
  }
  __syncthreads();
  red[t] = (tl < DD) ? mu[gh][tl] * agw[DD + tl] : 0.f;
  __syncthreads();
  for (int s = 128; s > 0; s >>= 1) { if (tl < s) red[t] += red[t + s]; __syncthreads(); }
  if (tl == 0) md[gh] = red[t] + agb[0];
  __syncthreads();
  float lgt;
  {
    const float* row = U + tl * DD;
    float s = 0.f;
    #pragma unroll 8
    for (int d2 = 0; d2 < DD; ++d2) s += row[d2] * agw[d2];
    lgt = s + md[gh];
  }
  red[t] = lgt;
  __syncthreads();
  for (int s = 128; s > 0; s >>= 1) { if (tl < s) red[t] = fmaxf(red[t], red[t + s]); __syncthreads(); }
  const float mx = red[gh << 8];
  __syncthreads();
  const float e = expf(lgt - mx);
  red[t] = e;
  __syncthreads();
  for (int s = 128; s > 0; s >>= 1) { if (tl < s) red[t] += red[t + s]; __syncthreads(); }
  const float sv = red[gh << 8];
  sg[t] = e / sv;
  __syncthreads();
  if (tl < DD) {
    float s = 0.f;
    for (int j = 0; j < NN; ++j) s += sg[(gh << 8) + j] * U[j * DD + tl];
    rr[gh][tl] = s;
  }
  __syncthreads();
  if (t < DD) {
    red[t]       = rr[0][t] * rr[1][t];
    red[t + 128] = rr[0][t] * rr[0][t];
    red[t + 256] = rr[1][t] * rr[1][t];
  }
  __syncthreads();
  for (int s = 64; s > 0; s >>= 1) {
    if (t < s) red[t] += red[t + s];
    if (t >= 128 && t < 128 + s) red[t] += red[t + s];
    if (t >= 256 && t < 256 + s) red[t] += red[t + s];
    __syncthreads();
  }
  if (t == 0) {
    const float den = fmaxf(sqrtf(red[128]) * sqrtf(red[256]), 1e-8f);
    out[0] = (red[0] / den + 1.f) * 0.5f;
  }
}

extern "C" void kernel_launch(void* const* d_in, const int* in_sizes, int n_in,
                              void* d_out, int out_size, void* d_ws, size_t ws_size,
                              hipStream_t stream)
{
  (void)in_sizes; (void)n_in; (void)out_size; (void)ws_size;
  const float* g1   = (const float*)d_in[0];
  const float* g2   = (const float*)d_in[1];
  const float* new1 = (const float*)d_in[2];
  const float* neb1 = (const float*)d_in[3];
  const float* new2 = (const float*)d_in[4];
  const float* neb2 = (const float*)d_in[5];
  const float* eew1 = (const float*)d_in[6];
  const float* eeb1 = (const float*)d_in[7];
  const float* eew2 = (const float*)d_in[8];
  const float* eeb2 = (const float*)d_in[9];
  const float* prw1 = (const float*)d_in[10];
  const float* prb1 = (const float*)d_in[11];
  const float* prw2 = (const float*)d_in[12];
  const float* prb2 = (const float*)d_in[13];
  const float* upw  = (const float*)d_in[14];
  const float* upb  = (const float*)d_in[15];
  const float* agw  = (const float*)d_in[16];
  const float* agb  = (const float*)d_in[17];
  float* W = (float*)d_ws;
  float* out = (float*)d_out;

  short* XW16  = (short*)(W + WS_XW);
  float* Xext  = W + WS_XEXT;
  short* W4f   = (short*)(W + WS_W4F);
  float* H1    = W + WS_H1;
  short* W2f   = (short*)(W + WS_W2F);
  short* WEf   = (short*)(W + WS_WEF);
  short* W1nf  = (short*)(W + WS_W1NF);
  short* W2nf  = (short*)(W + WS_W2NF);
  short* PW2f  = (short*)(W + WS_PW2F);
  float* emb   = W + WS_EMB;
  float* Sv    = W + WS_S;
  float* intra = W + WS_INTRA;
  float* crs   = W + WS_CROSS;
  float* updv  = W + WS_UPD;
  float* pb    = W + WS_PB;

  prep_pbk<<<2, 256, 0, stream>>>(eeb2, prw1, prb1, pb);
  xextk<<<512, 256, 0, stream>>>(g1, g2, Xext);
  swz5<<<dim3(128, 5), 64, 0, stream>>>(eew2, prw1, new1, new2, prw2, W);
  swz_w4<<<1664, 64, 0, stream>>>(eew1, prw1, eeb1, pb, W4f);
  // big4: XW[m][2048] = Xext @ W4  (Ae|Ce|Pp|Qm, bf16 out)
  gemmT<4, 1, 0><<<dim3(8, 8), 256, 0, stream>>>(Xext, 416, 1.f, W4f, 128, 13,
                                                 nullptr, (float*)XW16, 2048);
  // heavy fused per-edge pipeline -> S
  heavy_mfma<<<dim3(NN, 1, 2), 512, 0, stream>>>(XW16, W2f, WEf, Sv);
  // H1 = relu(x @ ne_w1 + ne_b1)   (overwrites W4f region)
  gemmT<2, 0, 1><<<dim3(8, 4), 256, 0, stream>>>(Xext, 416, 1.f, W1nf, 32, 4,
                                                 neb1, H1, 512);
  // emb = H1 @ ne_w2 + ne_b2
  gemmT<2, 0, 0><<<dim3(8, 1), 256, 0, stream>>>(H1, 512, 1.f, W2nf, 8, 16,
                                                 neb2, emb, 128);
  // intra = (S/N) @ pr_w2 + pr_b2
  gemmT<2, 0, 0><<<dim3(8, 1), 256, 0, stream>>>(Sv, 512, 1.f / 256.f, PW2f, 8, 16,
                                                 prb2, intra, 128);
  interactk<<<dim3(NN, 2), DD, 0, stream>>>(emb, crs);
  updk<<<dim3(NN, 1, 2), DD, 0, stream>>>(emb, intra, crs, upw, upb, updv);
  aggfinal<<<1, 512, 0, stream>>>(updv, agw, agb, out);
}

// Round 4
// 202.378 us; speedup vs baseline: 3.2221x; 1.3478x over previous
//
#include <hip/hip_runtime.h>
#include <math.h>

#define NN 256
#define DD 128
#define HH 512

// ---------------- workspace layout (float offsets) ----------------
#define WS_XW    0         // fp16 [2][256][2048] panel Ae|Ce|Pp|Qm   (524288 f)
#define WS_XEXT  524288    // [512][384] f32 (196608 f); dead after AB:
#define WS_EMB   524288    //   emb [2][256][128] (65536 f)
#define WS_INTRA 589824    //   intra [2][256][128] (65536 f)
#define WS_W4F   720896    // fp16 1536 frags x 512 halves (393216 f); dead after AB:
#define WS_UPD   720896    //   upd [2][256][128] (65536 f)
#define WS_H1    1114112   // [512][512] f32 (262144 f)
#define WS_S     1376256   // [2][256][512] f32 (262144 f)
#define WS_WB5   1638400   // fp16 5 x 128 frags (163840 f)
#define WS_B4    1802240   // bias4 [2048] f32
// total 1804288 floats = 6.88 MB

typedef __attribute__((ext_vector_type(8))) _Float16 half8;
typedef __attribute__((ext_vector_type(4))) _Float16 half4v;
typedef __attribute__((ext_vector_type(4))) float f32x4;

// ================= prep kernel: all swizzles + Xext + bias4 =================
// blocks [0,1536): W4f   [1536,2176): 5 small weights   [2176,2688): Xext
// [2688,2720): bias4
__global__ void prepk(const float* __restrict__ g1, const float* __restrict__ g2,
                      const float* __restrict__ eew1, const float* __restrict__ prw1,
                      const float* __restrict__ eeb1, const float* __restrict__ prb1,
                      const float* __restrict__ eeb2, const float* __restrict__ eew2,
                      const float* __restrict__ new1, const float* __restrict__ new2,
                      const float* __restrict__ prw2,
                      float* __restrict__ Xext, _Float16* __restrict__ W4f,
                      _Float16* __restrict__ Wb5, float* __restrict__ bias4)
{
  const int b = blockIdx.x, l = threadIdx.x;
  const int low = l & 15, q = l >> 4;
  if (b < 1536) {               // big-4 weight frags (K=384, N=2048)
    const int f = b;
    const int kcI = f >> 7, ntI = f & 127;
    const int n = ntI * 16 + low, slice = n >> 9, np = n & 511;
    const int kb = kcI * 32 + q * 8;
    half8 v;
    #pragma unroll
    for (int t = 0; t < 8; ++t) {
      const int k = kb + t;
      float val;
      if (slice == 0)      val = eew1[k * HH + np];
      else if (slice == 1) val = eew1[(384 + k) * HH + np];
      else if (slice == 2) val = (k < 128) ? prw1[k * HH + np] : 0.f;
      else                 val = (k < 128) ? prw1[(128 + k) * HH + np] : 0.f;
      v[t] = (_Float16)val;
    }
    *(half8*)&W4f[((size_t)f * 64 + l) * 8] = v;
  } else if (b < 2176) {        // five 128-frag weights
    const int idx = b - 1536;
    const int which = idx >> 7, f = idx & 127;
    const float* src; int ld, nt;
    switch (which) {
      case 0:  src = eew2;            ld = 128; nt = 8;  break;   // W2f
      case 1:  src = prw1 + 256 * HH; ld = 512; nt = 32; break;   // WEf
      case 2:  src = new1;            ld = 512; nt = 32; break;   // W1nf
      case 3:  src = new2;            ld = 128; nt = 8;  break;   // W2nf
      default: src = prw2;            ld = 128; nt = 8;  break;   // PW2f
    }
    _Float16* dst = Wb5 + (size_t)which * 65536;
    const int kcI = f / nt, ntI = f % nt;
    const int n = ntI * 16 + low;
    const int kb = kcI * 32 + q * 8;
    half8 v;
    #pragma unroll
    for (int t = 0; t < 8; ++t) v[t] = (_Float16)src[(kb + t) * ld + n];
    *(half8*)&dst[((size_t)f * 64 + l) * 8] = v;
  } else if (b < 2688) {        // Xext rows
    const int m = b - 2176;
    const int g = m >> 8, i = m & 255;
    const float* src = (g ? g2 : g1) + i * DD;
    float* dst = Xext + (size_t)m * 384;
    #pragma unroll
    for (int c = l; c < 384; c += 64)
      dst[c] = (c < 128) ? src[c] : ((c - 128 == i) ? 1.f : 0.f);
  } else {                      // bias4
    const int n = (b - 2688) * 64 + l;
    float v = 0.f;
    if (n < 512) v = eeb1[n];
    else if (n >= 1024 && n < 1536) {
      const int h = n - 1024;
      float s = prb1[h];
      #pragma unroll 8
      for (int d = 0; d < 128; ++d) s = fmaf(eeb2[d], prw1[(256 + d) * HH + h], s);
      v = s;
    }
    bias4[n] = v;
  }
}

// ================= dual-config transposed MFMA GEMM =================
// Out[m][n] = act( sc*Bsrc[m,:] @ W + bias[n] ); z = blockIdx.z picks config.
template<int FT>
__global__ __launch_bounds__(256, 2)
void gemm2(const float* B0, const float* B1, int ldb0, int ldb1,
           float sc0, float sc1,
           const _Float16* A0, const _Float16* A1, int nt0, int nt1,
           int kcn0, int kcn1, const float* bias0, const float* bias1,
           void* O0, void* O1, int ldo0, int ldo1,
           int half0, int half1, int relu0, int relu1, int ylim1)
{
  const int z = blockIdx.z;
  if (z == 1 && (int)blockIdx.y >= ylim1) return;
  const float* Bsrc = z ? B1 : B0;
  const _Float16* Af = z ? A1 : A0;
  const float* bias = z ? bias1 : bias0;
  void* Out = z ? O1 : O0;
  const int ldb = z ? ldb1 : ldb0, ntTot = z ? nt1 : nt0;
  const int kcN = z ? kcn1 : kcn0, ldo = z ? ldo1 : ldo0;
  const int ohalf = z ? half1 : half0, orelu = z ? relu1 : relu0;
  const float sc = z ? sc1 : sc0;

  const int tid = threadIdx.x;
  const int w = tid >> 6, l = tid & 63, low = l & 15, q = l >> 4;
  const int mb = blockIdx.x * 64;
  const int nb = (blockIdx.y * 4 + w) * (FT * 16);
  f32x4 acc[FT][4];
  #pragma unroll
  for (int ft = 0; ft < FT; ++ft)
    #pragma unroll
    for (int et = 0; et < 4; ++et) acc[ft][et] = (f32x4){0.f, 0.f, 0.f, 0.f};

  for (int kc = 0; kc < kcN; ++kc) {
    const int k0 = kc * 32 + q * 8;
    half8 bfr[4];
    #pragma unroll
    for (int et = 0; et < 4; ++et) {
      const float* p = Bsrc + (size_t)(mb + et * 16 + low) * ldb + k0;
      const float4 b0 = *(const float4*)p;
      const float4 b1 = *(const float4*)(p + 4);
      half8 v;
      v[0] = (_Float16)(b0.x * sc); v[1] = (_Float16)(b0.y * sc);
      v[2] = (_Float16)(b0.z * sc); v[3] = (_Float16)(b0.w * sc);
      v[4] = (_Float16)(b1.x * sc); v[5] = (_Float16)(b1.y * sc);
      v[6] = (_Float16)(b1.z * sc); v[7] = (_Float16)(b1.w * sc);
      bfr[et] = v;
    }
    #pragma unroll
    for (int ft = 0; ft < FT; ++ft) {
      const int ng = (nb >> 4) + ft;
      const half8 af = *(const half8*)&Af[((size_t)(kc * ntTot + ng) * 64 + l) * 8];
      #pragma unroll
      for (int et = 0; et < 4; ++et)
        acc[ft][et] = __builtin_amdgcn_mfma_f32_16x16x32_f16(af, bfr[et], acc[ft][et], 0, 0, 0);
    }
  }
  #pragma unroll
  for (int ft = 0; ft < FT; ++ft) {
    const int n0 = nb + ft * 16 + q * 4;
    const float4 bs = *(const float4*)&bias[n0];
    #pragma unroll
    for (int et = 0; et < 4; ++et) {
      const int m = mb + et * 16 + low;
      float vx = acc[ft][et][0] + bs.x;
      float vy = acc[ft][et][1] + bs.y;
      float vz = acc[ft][et][2] + bs.z;
      float vw = acc[ft][et][3] + bs.w;
      if (orelu) {
        vx = fmaxf(vx, 0.f); vy = fmaxf(vy, 0.f);
        vz = fmaxf(vz, 0.f); vw = fmaxf(vw, 0.f);
      }
      if (ohalf) {
        half4v pk;
        pk[0] = (_Float16)vx; pk[1] = (_Float16)vy;
        pk[2] = (_Float16)vz; pk[3] = (_Float16)vw;
        *(half4v*)((_Float16*)Out + (size_t)m * ldo + n0) = pk;
      } else {
        *(float4*)((float*)Out + (size_t)m * ldo + n0) = make_float4(vx, vy, vz, vw);
      }
    }
  }
}

// ================= fused heavy edge kernel (fp16 MFMA) =================
// block: 1 i x 256 j, 8 waves; wave w owns e in [32w, 32w+32). LDS ~69KB.
__global__ __launch_bounds__(512, 4)
void heavy_mfma(const _Float16* __restrict__ XW, const _Float16* __restrict__ W2f,
                const _Float16* __restrict__ WEf, float* __restrict__ SG)
{
  __shared__ _Float16 Ut[NN * DD];     // 64 KB, XOR-swizzled 8B blocks (wave-private rows)
  __shared__ _Float16 AeH[HH];         // 1 KB
  __shared__ float PpL[HH];            // 2 KB
  __shared__ float SAcc[HH];           // 2 KB
  const int g = blockIdx.z, i = blockIdx.x, tid = threadIdx.x;
  const _Float16* Xg = XW + (size_t)g * NN * 2048;
  const _Float16* rowI = Xg + (size_t)i * 2048;
  AeH[tid] = rowI[tid];
  PpL[tid] = (float)rowI[1024 + tid];
  SAcc[tid] = 0.f;
  __syncthreads();

  const int w = tid >> 6, l = tid & 63, low = l & 15, q = l >> 4;
  const int ebase = w << 5;
  const int xsw = (low & 7) << 1;
  const half8 hz = (half8)((_Float16)0);

  // ---------- stage 1: Ut[e][c] = fp16( sum_k relu(Ae[k]+Ce[j][k]) * W2[k][c] ) ----------
  {
    f32x4 acc[8][2];
    #pragma unroll
    for (int ct = 0; ct < 8; ++ct) {
      acc[ct][0] = (f32x4){0.f, 0.f, 0.f, 0.f};
      acc[ct][1] = (f32x4){0.f, 0.f, 0.f, 0.f};
    }
    for (int kc = 0; kc < 16; ++kc) {
      const int k0 = kc * 32 + q * 8;
      const half8 a = *(const half8*)&AeH[k0];
      half8 bfr[2];
      #pragma unroll
      for (int et = 0; et < 2; ++et) {
        const int j = ebase + et * 16 + low;
        const half8 c = *(const half8*)&Xg[(size_t)j * 2048 + 512 + k0];
        bfr[et] = __builtin_elementwise_max(a + c, hz);   // v_pk_add + v_pk_max
      }
      __builtin_amdgcn_s_setprio(1);
      #pragma unroll
      for (int ct = 0; ct < 8; ++ct) {
        const half8 af = *(const half8*)&W2f[((size_t)(kc * 8 + ct) * 64 + l) * 8];
        acc[ct][0] = __builtin_amdgcn_mfma_f32_16x16x32_f16(af, bfr[0], acc[ct][0], 0, 0, 0);
        acc[ct][1] = __builtin_amdgcn_mfma_f32_16x16x32_f16(af, bfr[1], acc[ct][1], 0, 0, 0);
      }
      __builtin_amdgcn_s_setprio(0);
    }
    #pragma unroll
    for (int ct = 0; ct < 8; ++ct)
      #pragma unroll
      for (int et = 0; et < 2; ++et) {
        const int e = ebase + et * 16 + low;
        const int cb = ct * 4 + q;
        half4v pk;
        pk[0] = (_Float16)acc[ct][et][0]; pk[1] = (_Float16)acc[ct][et][1];
        pk[2] = (_Float16)acc[ct][et][2]; pk[3] = (_Float16)acc[ct][et][3];
        *(half4v*)&Ut[e * DD + ((cb ^ xsw) << 2)] = pk;
      }
  }
  // no barrier: Ut rows are wave-private (within-wave lgkmcnt ordering suffices)

  // ---------- stage 2: G^T = WE^T * U^T; relu(Pp+Qm+G) summed over e ----------
  for (int hc = 0; hc < 4; ++hc) {
    #pragma unroll
    for (int hp = 0; hp < 2; ++hp) {
      f32x4 acc2[4][2];
      #pragma unroll
      for (int ht = 0; ht < 4; ++ht) {
        acc2[ht][0] = (f32x4){0.f, 0.f, 0.f, 0.f};
        acc2[ht][1] = (f32x4){0.f, 0.f, 0.f, 0.f};
      }
      #pragma unroll
      for (int kc2 = 0; kc2 < 4; ++kc2) {
        const int cb0 = kc2 * 8 + q * 2;
        const half8 b0 = *(const half8*)&Ut[(ebase + low) * DD + ((cb0 ^ xsw) << 2)];
        const half8 b1 = *(const half8*)&Ut[(ebase + 16 + low) * DD + ((cb0 ^ xsw) << 2)];
        __builtin_amdgcn_s_setprio(1);
        #pragma unroll
        for (int ht = 0; ht < 4; ++ht) {
          const int hg = hc * 8 + hp * 4 + ht;
          const half8 af = *(const half8*)&WEf[((size_t)(kc2 * 32 + hg) * 64 + l) * 8];
          acc2[ht][0] = __builtin_amdgcn_mfma_f32_16x16x32_f16(af, b0, acc2[ht][0], 0, 0, 0);
          acc2[ht][1] = __builtin_amdgcn_mfma_f32_16x16x32_f16(af, b1, acc2[ht][1], 0, 0, 0);
        }
        __builtin_amdgcn_s_setprio(0);
      }
      #pragma unroll
      for (int ht = 0; ht < 4; ++ht) {
        const int h0 = hc * 128 + (hp * 4 + ht) * 16 + q * 4;
        const float4 pp = *(const float4*)&PpL[h0];
        float pr[4] = {0.f, 0.f, 0.f, 0.f};
        #pragma unroll
        for (int et = 0; et < 2; ++et) {
          const int j = ebase + et * 16 + low;
          const half4v qm = *(const half4v*)&Xg[(size_t)j * 2048 + 1536 + h0];
          pr[0] += fmaxf(pp.x + (float)qm[0] + acc2[ht][et][0], 0.f);
          pr[1] += fmaxf(pp.y + (float)qm[1] + acc2[ht][et][1], 0.f);
          pr[2] += fmaxf(pp.z + (float)qm[2] + acc2[ht][et][2], 0.f);
          pr[3] += fmaxf(pp.w + (float)qm[3] + acc2[ht][et][3], 0.f);
        }
        #pragma unroll
        for (int r = 0; r < 4; ++r) {
          float v = pr[r];
          v += __shfl_xor(v, 1);
          v += __shfl_xor(v, 2);
          v += __shfl_xor(v, 4);
          v += __shfl_xor(v, 8);
          if (low == 0) atomicAdd(&SAcc[h0 + r], v);
        }
      }
    }
  }
  __syncthreads();
  SG[((size_t)g * NN + i) * HH + tid] = SAcc[tid];
}

// ============ fused interact + l2norm + update (cross never stored) ============
__global__ void interupd(const float* __restrict__ embG, const float* __restrict__ intraG,
                         const float* __restrict__ upw, const float* __restrict__ upb,
                         float* __restrict__ updG)
{
  const int i = blockIdx.x, dir = blockIdx.y, d = threadIdx.x; // 128 threads
  const float* A = embG + dir * NN * DD;
  const float* Bp = embG + (1 - dir) * NN * DD;
  const float av = A[i * DD + d];
  float accN = 0.f, accS = 0.f;
  #pragma unroll 4
  for (int j = 0; j < NN; ++j) {
    const float bv = Bp[j * DD + d];
    accN = fmaf(bv, __expf(av * bv), accN);
    accS += bv;
  }
  const float cv = accN / (256.f * av * accS);
  const float iv = intraG[dir * NN * DD + i * DD + d];

  __shared__ float pw[2][4];
  float q0 = av * av, q1 = iv * iv, q2 = cv * cv;
  #pragma unroll
  for (int st = 1; st < 64; st <<= 1) {
    q0 += __shfl_xor(q0, st);
    q1 += __shfl_xor(q1, st);
    q2 += __shfl_xor(q2, st);
  }
  const int w = d >> 6;
  if ((d & 63) == 0) { pw[w][0] = q0; pw[w][1] = q1; pw[w][2] = q2; }
  __syncthreads();
  const float n0 = 1.f / fmaxf(sqrtf(pw[0][0] + pw[1][0]), 1e-12f);
  const float n1 = 1.f / fmaxf(sqrtf(pw[0][1] + pw[1][1]), 1e-12f);
  const float n2 = 1.f / fmaxf(sqrtf(pw[0][2] + pw[1][2]), 1e-12f);
  __shared__ float vsm[3 * DD];
  vsm[d] = av * n0; vsm[DD + d] = iv * n1; vsm[2 * DD + d] = cv * n2;
  __syncthreads();
  float acc = upb[d];
  #pragma unroll 8
  for (int k = 0; k < 3 * DD; ++k) acc = fmaf(vsm[k], upw[k * DD + d], acc);
  updG[dir * NN * DD + i * DD + d] = acc;
}

// ============ aggregate both graphs + cosine, j-parallel, 512 threads ============
__global__ void aggfin(const float* __restrict__ updG, const float* __restrict__ agw,
                       const float* __restrict__ agb, float* __restrict__ out)
{
  __shared__ float mp[2][2][DD];
  __shared__ float sg[2][NN];
  __shared__ float redd[512];
  const int t = threadIdx.x;
  const int g = t >> 8, tl = t & 255, jc = tl >> 7, d = tl & 127;
  const float* U = updG + g * NN * DD;
  // mu partials
  {
    float s = 0.f;
    for (int j = jc * 128; j < jc * 128 + 128; ++j) s += U[j * DD + d];
    mp[g][jc][d] = s;
  }
  __syncthreads();
  if (jc == 0) {
    const float mu = (mp[g][0][d] + mp[g][1][d]) * (1.f / 256.f);
    redd[g * 256 + d] = mu * agw[DD + d];
  }
  __syncthreads();
  for (int st = 64; st > 0; st >>= 1) {
    if (jc == 0 && d < st) redd[g * 256 + d] += redd[g * 256 + d + st];
    __syncthreads();
  }
  const float mdot = redd[g << 8] + agb[0];
  __syncthreads();
  // logits, one j per thread
  float lg = mdot;
  {
    const float* row = U + tl * DD;
    float s = 0.f;
    #pragma unroll 8
    for (int d2 = 0; d2 < DD; ++d2) s = fmaf(row[d2], agw[d2], s);
    lg += s;
  }
  redd[t] = lg;
  __syncthreads();
  for (int st = 128; st > 0; st >>= 1) {
    if (tl < st) redd[t] = fmaxf(redd[t], redd[t + st]);
    __syncthreads();
  }
  const float mx = redd[g << 8];
  __syncthreads();
  const float e = __expf(lg - mx);
  redd[t] = e;
  __syncthreads();
  for (int st = 128; st > 0; st >>= 1) {
    if (tl < st) redd[t] += redd[t + st];
    __syncthreads();
  }
  sg[g][tl] = e / redd[g << 8];
  __syncthreads();
  // r partials
  {
    float rp = 0.f;
    for (int j = jc * 128; j < jc * 128 + 128; ++j) rp = fmaf(sg[g][j], U[j * DD + d], rp);
    mp[g][jc][d] = rp;
  }
  __syncthreads();
  if (t < DD) {
    const float r0 = mp[0][0][t] + mp[0][1][t];
    const float r1 = mp[1][0][t] + mp[1][1][t];
    redd[t] = r0 * r1; redd[128 + t] = r0 * r0; redd[256 + t] = r1 * r1;
  }
  __syncthreads();
  for (int st = 64; st > 0; st >>= 1) {
    if (t < st) redd[t] += redd[t + st];
    else if (t >= 128 && t < 128 + st) redd[t] += redd[t + st];
    else if (t >= 256 && t < 256 + st) redd[t] += redd[t + st];
    __syncthreads();
  }
  if (t == 0)
    out[0] = (redd[0] / fmaxf(sqrtf(redd[128]) * sqrtf(redd[256]), 1e-8f) + 1.f) * 0.5f;
}

extern "C" void kernel_launch(void* const* d_in, const int* in_sizes, int n_in,
                              void* d_out, int out_size, void* d_ws, size_t ws_size,
                              hipStream_t stream)
{
  (void)in_sizes; (void)n_in; (void)out_size; (void)ws_size;
  const float* g1   = (const float*)d_in[0];
  const float* g2   = (const float*)d_in[1];
  const float* new1 = (const float*)d_in[2];
  const float* neb1 = (const float*)d_in[3];
  const float* new2 = (const float*)d_in[4];
  const float* neb2 = (const float*)d_in[5];
  const float* eew1 = (const float*)d_in[6];
  const float* eeb1 = (const float*)d_in[7];
  const float* eew2 = (const float*)d_in[8];
  const float* eeb2 = (const float*)d_in[9];
  const float* prw1 = (const float*)d_in[10];
  const float* prb1 = (const float*)d_in[11];
  const float* prw2 = (const float*)d_in[12];
  const float* prb2 = (const float*)d_in[13];
  const float* upw  = (const float*)d_in[14];
  const float* upb  = (const float*)d_in[15];
  const float* agw  = (const float*)d_in[16];
  const float* agb  = (const float*)d_in[17];
  float* W = (float*)d_ws;
  float* out = (float*)d_out;

  _Float16* XW16 = (_Float16*)(W + WS_XW);
  float* Xext    = W + WS_XEXT;
  float* emb     = W + WS_EMB;
  float* intra   = W + WS_INTRA;
  _Float16* W4f  = (_Float16*)(W + WS_W4F);
  float* updv    = W + WS_UPD;
  float* H1      = W + WS_H1;
  float* Sv      = W + WS_S;
  _Float16* Wb5  = (_Float16*)(W + WS_WB5);
  float* bias4   = W + WS_B4;
  _Float16* W2f  = Wb5;
  _Float16* WEf  = Wb5 + 65536;
  _Float16* W1nf = Wb5 + 2 * 65536;
  _Float16* W2nf = Wb5 + 3 * 65536;
  _Float16* PW2f = Wb5 + 4 * 65536;

  // 1. all preprocessing (weight swizzles, Xext, fused bias vector)
  prepk<<<2720, 64, 0, stream>>>(g1, g2, eew1, prw1, eeb1, prb1, eeb2,
                                 eew2, new1, new2, prw2,
                                 Xext, W4f, Wb5, bias4);
  // 2. AB: z0 = big4 panel (fp16 out), z1 = H1 (relu, f32)
  gemm2<4><<<dim3(8, 8, 2), 256, 0, stream>>>(
      Xext, Xext, 384, 384, 1.f, 1.f,
      W4f, W1nf, 128, 32, 12, 4, bias4, neb1,
      (void*)XW16, (void*)H1, 2048, 512, 1, 0, 0, 1, 2);
  // 3. heavy fused per-edge pipeline -> S
  heavy_mfma<<<dim3(NN, 1, 2), 512, 0, stream>>>(XW16, W2f, WEf, Sv);
  // 4. CD: z0 = emb (H1 @ ne_w2 + b), z1 = intra ((S/256) @ pr_w2 + b)
  gemm2<2><<<dim3(8, 1, 2), 256, 0, stream>>>(
      H1, Sv, 512, 512, 1.f, 1.f / 256.f,
      W2nf, PW2f, 8, 8, 16, 16, neb2, prb2,
      (void*)emb, (void*)intra, 128, 128, 0, 0, 0, 0, 1);
  // 5. interact + l2norms + update (cross kept in registers)
  interupd<<<dim3(NN, 2), DD, 0, stream>>>(emb, intra, upw, upb, updv);
  // 6. aggregate + cosine
  aggfin<<<1, 512, 0, stream>>>(updv, agw, agb, out);
}